// Round 7
// baseline (91.168 us; speedup 1.0000x reference)
//
#include <hip/hip_runtime.h>

#define BN 4096
#define SZ 2048
#define HIDN 128
#define NT 8
#define PADROWS 4384             // 4096 + 9*32 padding
#define PADTILES (PADROWS / 16)  // 274

typedef __bf16 bf16_t;
typedef bf16_t bf16x8 __attribute__((ext_vector_type(8)));
typedef float f32x4 __attribute__((ext_vector_type(4)));

__device__ inline bf16_t f2b(float f) {
    unsigned u = __builtin_bit_cast(unsigned, f);
    unsigned short s = (unsigned short)((u + 0x7fffu + ((u >> 16) & 1u)) >> 16);
    return __builtin_bit_cast(bf16_t, s);
}

// ws layout (bytes):
//   idxb int[PADROWS] @0
//   meta              @17664  [0..8]=cnt, [16..25]=padded offs
//   HbP  bf16 frag    @18432  [rt(274)][kf(4)][lane(64)][8]   (~1.1 MB)
//   WdP  bf16 frag    @1140736 [t][hf(8)][kt(64)][lane][8]    (4 MB)
//   WuP  bf16 frag    @5335040 [t][cf(128)][kf(4)][lane][8]   (4 MB)

// ---- prep: blocks 0..1023 pack weights; block 1024 buckets (ballot-based) ----
__global__ __launch_bounds__(256) void k_prep(const float* __restrict__ Wd,
                                              const float* __restrict__ Wu,
                                              const int* __restrict__ task,
                                              bf16_t* __restrict__ WdP,
                                              bf16_t* __restrict__ WuP,
                                              int* __restrict__ meta,
                                              int* __restrict__ idxb) {
    int bid = blockIdx.x, tid = threadIdx.x;
    if (bid == 1024) {  // ---- bucketing, 256 threads = 4 waves, 16 items/thread ----
        __shared__ int wcnt[16][4][9];   // [iter][wave][bucket] -> in-place prefix
        __shared__ int cnt[9], off[10], sflag;
        int lane = tid & 63, w = tid >> 6;
        unsigned long long ltmask = (1ull << lane) - 1ull;
        if (tid < 64) {
            int v = task[2 * tid + 1];
            bool ok = (v == 0 || v == -1);   // int64 detection via sign-ext words
            unsigned long long m = __ballot(ok);
            if (tid == 0) sflag = (m == ~0ull) ? 1 : 0;
        }
        __syncthreads();
        int f = sflag;
        int bks[16];
#pragma unroll
        for (int it = 0; it < 16; it++) {
            int b = it * 256 + tid;
            int t = f ? task[2 * b] : task[b];
            int bk = (t < 0) ? 8 : (t > 7 ? 7 : t);
            bks[it] = bk;
#pragma unroll
            for (int bu = 0; bu < 9; bu++) {
                unsigned long long m = __ballot(bk == bu);
                if (lane == 0) wcnt[it][w][bu] = (int)__popcll(m);
            }
        }
        __syncthreads();
        if (tid < 9) {   // in-place prefix over (it, w) order; totals -> cnt
            int s = 0;
#pragma unroll
            for (int it = 0; it < 16; it++)
#pragma unroll
                for (int ww = 0; ww < 4; ww++) {
                    int p = wcnt[it][ww][tid];
                    wcnt[it][ww][tid] = s;
                    s += p;
                }
            cnt[tid] = s;
        }
        __syncthreads();
        if (tid == 0) {
            int s = 0;
            for (int i = 0; i < 9; i++) { off[i] = s; s += (cnt[i] + 31) & ~31; }
            off[9] = s;
        }
        __syncthreads();
#pragma unroll
        for (int it = 0; it < 16; it++) {
            int bk = bks[it];
            unsigned long long mymask = 0;
#pragma unroll
            for (int bu = 0; bu < 9; bu++) {
                unsigned long long m = __ballot(bk == bu);
                if (bk == bu) mymask = m;
            }
            int rank = (int)__popcll(mymask & ltmask);
            int pos = off[bk] + wcnt[it][w][bk] + rank;
            idxb[pos] = it * 256 + tid;
        }
        if (tid < 9) meta[tid] = cnt[tid];
        if (tid >= 16 && tid < 26) meta[tid] = off[tid - 16];
        return;
    }
    // ---- weight pack (fp32 -> bf16 fragment layout) ----
    __shared__ float tile[32][132];
    const float* src;
    bf16_t* dst;
    int fragstride;
    size_t rowstride;
    if (bid < 512) {
        int t = bid >> 6, kt = bid & 63;
        src = Wd + ((size_t)t * SZ + kt * 32) * HIDN;
        rowstride = HIDN;
        dst = WdP + ((size_t)(t * 8) * 64 + kt) * 512;
        fragstride = 64 * 512;
    } else {
        int lb = bid - 512;
        int t = lb >> 6, rem = lb & 63;
        int kf = rem >> 4, cch = rem & 15;
        src = Wu + ((size_t)t * HIDN + kf * 32) * SZ + cch * 128;
        rowstride = SZ;
        dst = WuP + ((size_t)(t * 128 + cch * 8) * 4 + kf) * 512;
        fragstride = 4 * 512;
    }
#pragma unroll
    for (int i = 0; i < 4; i++) {
        int row = (tid >> 5) + 8 * i, quad = tid & 31;
        f32x4 v = *(const f32x4*)(src + (size_t)row * rowstride + quad * 4);
        tile[row][quad * 4 + 0] = v.x; tile[row][quad * 4 + 1] = v.y;
        tile[row][quad * 4 + 2] = v.z; tile[row][quad * 4 + 3] = v.w;
    }
    __syncthreads();
    int w = tid >> 6, lane = tid & 63, lr = lane & 15, lq = lane >> 4;
#pragma unroll
    for (int ii = 0; ii < 2; ii++) {
        int hf = w * 2 + ii;
        bf16x8 o;
#pragma unroll
        for (int j = 0; j < 8; j++) {
            int kloc = (j < 4) ? (4 * lq + j) : (16 + 4 * lq + j - 4);
            o[j] = f2b(tile[kloc][hf * 16 + lr]);
        }
        *(bf16x8*)(dst + (size_t)hf * fragstride + lane * 8) = o;
    }
}

// ---- GEMM1 fused: HbP[rt] = silu(x[g(r)][:] . Wd[t] + bd[t]) in A-frag layout ----
// grid = 8*256; t = bid&7 (XCD pin), tile = bid>>3 (16 rows each); 4 waves x 2 hf
__global__ __launch_bounds__(256) void k_gemm1(const float* __restrict__ x,
                                               const bf16_t* __restrict__ WdP,
                                               const float* __restrict__ bd,
                                               const int* __restrict__ idxb,
                                               const int* __restrict__ meta,
                                               bf16_t* __restrict__ HbP) {
    int bid = blockIdx.x;
    int t = bid & 7, tile = bid >> 3;
    int n = meta[t];
    int r0 = tile * 16;
    if (r0 >= n) return;
    int base = meta[16 + t];
    int tid = threadIdx.x, lane = tid & 63, w = tid >> 6;
    int lr = lane & 15, lq = lane >> 4;

    int br = r0 + lr;
    int g = idxb[base + (br < n ? br : n - 1)];
    const float* xrow = x + (size_t)g * SZ + 4 * lq;
    const bf16_t* wb = WdP + ((size_t)(t * 8 + w * 2) * 64) * 512 + lane * 8;

    f32x4 acc[2] = {};
#pragma unroll 8
    for (int kfi = 0; kfi < 64; kfi++) {
        f32x4 lo = *(const f32x4*)(xrow + kfi * 32);
        f32x4 hi = *(const f32x4*)(xrow + kfi * 32 + 16);
        bf16x8 a;
        a[0] = f2b(lo.x); a[1] = f2b(lo.y); a[2] = f2b(lo.z); a[3] = f2b(lo.w);
        a[4] = f2b(hi.x); a[5] = f2b(hi.y); a[6] = f2b(hi.z); a[7] = f2b(hi.w);
        bf16x8 b0 = *(const bf16x8*)(wb + (size_t)kfi * 512);
        bf16x8 b1 = *(const bf16x8*)(wb + (size_t)(64 + kfi) * 512);
        acc[0] = __builtin_amdgcn_mfma_f32_16x16x32_bf16(a, b0, acc[0], 0, 0, 0);
        acc[1] = __builtin_amdgcn_mfma_f32_16x16x32_bf16(a, b1, acc[1], 0, 0, 0);
    }

    // bias + silu, bounce through LDS (C-layout -> A-frag layout), +4 pad vs conflicts
    __shared__ bf16_t hl[16][132];
#pragma unroll
    for (int f = 0; f < 2; f++) {
        int h = w * 32 + f * 16 + lr;
        float bb = bd[t * HIDN + h];
#pragma unroll
        for (int reg = 0; reg < 4; reg++) {
            float v = acc[f][reg] + bb;
            hl[4 * lq + reg][h] = f2b(v / (1.f + __expf(-v)));
        }
    }
    __syncthreads();
    int rt = (base + r0) >> 4;
    bf16x8 o;
#pragma unroll
    for (int j = 0; j < 8; j++) {
        int k = w * 32 + ((j < 4) ? (4 * lq + j) : (16 + 4 * lq + j - 4));
        o[j] = hl[lr][k];
    }
    *(bf16x8*)(HbP + ((size_t)(rt * 4 + w) * 64 + lane) * 8) = o;
}

// ---- GEMM2 + residual + passthrough tail ----
// bid<8192: t = bid&7 (XCD pin), tile = (bid>>3)&127, cchunk = bid>>10
// bid>=8192: passthrough (bucket 8)
__global__ __launch_bounds__(256) void k_gemm2(const float* __restrict__ x,
                                               const bf16_t* __restrict__ WuP,
                                               const float* __restrict__ bu,
                                               const bf16_t* __restrict__ HbP,
                                               const int* __restrict__ idxb,
                                               const int* __restrict__ meta,
                                               float* __restrict__ out) {
    int bid = blockIdx.x;
    int tid = threadIdx.x;
    if (bid >= 8192) {
        int pb = bid - 8192;
        int n8 = meta[8];
        int tile = pb & 127, half = pb >> 7;
        int r0 = tile * 32;
        if (r0 >= n8) return;
        int base8 = meta[16 + 8];
        int row = tid >> 3, cq = tid & 7;
        int r = r0 + row;
        if (r < n8) {
            int g = idxb[base8 + r];
            const f32x4* xs = (const f32x4*)(x + (size_t)g * SZ + half * 256) + cq;
            f32x4* os = (f32x4*)(out + (size_t)g * SZ + half * 256) + cq;
#pragma unroll
            for (int j = 0; j < 8; j++) __builtin_nontemporal_store(xs[j * 8], &os[j * 8]);
        }
        return;
    }
    int t = bid & 7, tile = (bid >> 3) & 127, cchunk = bid >> 10;
    int n = meta[t];
    int r0 = tile * 32;
    if (r0 >= n) return;
    int base = meta[16 + t];
    int lane = tid & 63, w = tid >> 6;
    int wr = w & 1, wc = w >> 1, lr = lane & 15, lq = lane >> 4;

    int rt = (base + r0) / 16 + wr;           // base is 32-aligned
    const bf16_t* ap = HbP + (size_t)rt * 4 * 512 + lane * 8;
    bf16x8 a[4];
#pragma unroll
    for (int kf = 0; kf < 4; kf++) a[kf] = *(const bf16x8*)(ap + kf * 512);

    const bf16_t* bp = WuP + ((size_t)(t * 128 + cchunk * 16 + wc * 8) * 4) * 512 + lane * 8;
    f32x4 acc[8] = {};
#pragma unroll
    for (int cf = 0; cf < 8; cf++) {
#pragma unroll
        for (int kf = 0; kf < 4; kf++) {
            bf16x8 b = *(const bf16x8*)(bp + (size_t)(cf * 4 + kf) * 512);
            acc[cf] = __builtin_amdgcn_mfma_f32_16x16x32_bf16(a[kf], b, acc[cf], 0, 0, 0);
        }
    }

    int gr[4];
#pragma unroll
    for (int reg = 0; reg < 4; reg++) {
        int r = r0 + wr * 16 + 4 * lq + reg;
        gr[reg] = (r < n) ? idxb[base + r] : -1;
    }
#pragma unroll
    for (int cf = 0; cf < 8; cf++) {
        int c = cchunk * 256 + wc * 128 + cf * 16 + lr;
        float bb = bu[t * SZ + c];
#pragma unroll
        for (int reg = 0; reg < 4; reg++) {
            if (gr[reg] >= 0) {
                size_t o = (size_t)gr[reg] * SZ + c;
                __builtin_nontemporal_store(x[o] + acc[cf][reg] + bb, &out[o]);
            }
        }
    }
}

extern "C" void kernel_launch(void* const* d_in, const int* in_sizes, int n_in,
                              void* d_out, int out_size, void* d_ws, size_t ws_size,
                              hipStream_t stream) {
    const float* x  = (const float*)d_in[0];
    const float* Wd = (const float*)d_in[1];
    const float* bd = (const float*)d_in[2];
    const float* Wu = (const float*)d_in[3];
    const float* bu = (const float*)d_in[4];
    const int* task = (const int*)d_in[5];
    float* out = (float*)d_out;

    char* ws = (char*)d_ws;
    int* idxb    = (int*)ws;
    int* meta    = (int*)(ws + 17664);
    bf16_t* HbP  = (bf16_t*)(ws + 18432);
    bf16_t* WdP  = (bf16_t*)(ws + 1140736);
    bf16_t* WuP  = (bf16_t*)(ws + 5335040);

    k_prep<<<1025, 256, 0, stream>>>(Wd, Wu, task, WdP, WuP, meta, idxb);
    k_gemm1<<<8 * 256, 256, 0, stream>>>(x, WdP, bd, idxb, meta, HbP);
    k_gemm2<<<8192 + 1024, 256, 0, stream>>>(x, WuP, bu, HbP, idxb, meta, out);
}

// Round 8
// 82.315 us; speedup vs baseline: 1.1076x; 1.1076x over previous
//
#include <hip/hip_runtime.h>

#define BN 4096
#define SZ 2048
#define HIDN 128
#define NT 8
#define PADROWS 4384             // 4096 + 9*32 padding
#define PADTILES (PADROWS / 16)  // 274

typedef __bf16 bf16_t;
typedef bf16_t bf16x8 __attribute__((ext_vector_type(8)));
typedef float f32x4 __attribute__((ext_vector_type(4)));

__device__ inline bf16_t f2b(float f) {
    unsigned u = __builtin_bit_cast(unsigned, f);
    unsigned short s = (unsigned short)((u + 0x7fffu + ((u >> 16) & 1u)) >> 16);
    return __builtin_bit_cast(bf16_t, s);
}

// ws layout (bytes):
//   idxb  int[PADROWS] @0          (17536 B)
//   meta  int[64]      @17664      [0..8]=cnt, [16..25]=padded offs
//   cnt16 int[16*9]    @17920      per-hist-block bucket counts
//   HbP   bf16 frag    @18560      [rt(274)][kf(4)][lane(64)][8]  (~1.1 MB)
//   WdP   bf16 frag    @1140864    [t][hf(8)][kt(64)][lane][8]    (4 MB)
//   WuP   bf16 frag    @5335168    [t][cf(128)][kf(4)][lane][8]   (4 MB)

__device__ inline int detect_i64(const int* task, int tid, int* sflag) {
    // sample 64 odd words; int64 -> all are 0/-1 sign extensions
    if (tid < 64) {
        int v = task[2 * tid + 1];
        bool ok = (v == 0 || v == -1);
        unsigned long long m = __ballot(ok);
        if (tid == 0) *sflag = (m == ~0ull) ? 1 : 0;
    }
    return 0;
}

// ---- prep: blocks 0..1023 pack weights; blocks 1024..1039 histogram ----
__global__ __launch_bounds__(256) void k_prep(const float* __restrict__ Wd,
                                              const float* __restrict__ Wu,
                                              const int* __restrict__ task,
                                              bf16_t* __restrict__ WdP,
                                              bf16_t* __restrict__ WuP,
                                              int* __restrict__ cnt16g) {
    int bid = blockIdx.x, tid = threadIdx.x;
    __shared__ int wv[4][9], sflag;
    if (bid >= 1024) {  // ---- histogram: 16 blocks, 256 items each ----
        int blk = bid - 1024;
        int lane = tid & 63, w = tid >> 6;
        detect_i64(task, tid, &sflag);
        __syncthreads();
        int f = sflag;
        int item = blk * 256 + tid;
        int tv = f ? task[2 * item] : task[item];
        int bk = (tv < 0) ? 8 : (tv > 7 ? 7 : tv);
#pragma unroll
        for (int bu = 0; bu < 9; bu++) {
            unsigned long long m = __ballot(bk == bu);
            if (lane == 0) wv[w][bu] = (int)__popcll(m);
        }
        __syncthreads();
        if (tid < 9) {
            int s = 0;
#pragma unroll
            for (int ww = 0; ww < 4; ww++) s += wv[ww][tid];
            cnt16g[blk * 9 + tid] = s;
        }
        return;
    }
    // ---- weight pack (fp32 -> bf16 fragment layout) ----
    __shared__ float tile[32][132];
    const float* src;
    bf16_t* dst;
    int fragstride;
    size_t rowstride;
    if (bid < 512) {
        int t = bid >> 6, kt = bid & 63;
        src = Wd + ((size_t)t * SZ + kt * 32) * HIDN;
        rowstride = HIDN;
        dst = WdP + ((size_t)(t * 8) * 64 + kt) * 512;
        fragstride = 64 * 512;
    } else {
        int lb = bid - 512;
        int t = lb >> 6, rem = lb & 63;
        int kf = rem >> 4, cch = rem & 15;
        src = Wu + ((size_t)t * HIDN + kf * 32) * SZ + cch * 128;
        rowstride = SZ;
        dst = WuP + ((size_t)(t * 128 + cch * 8) * 4 + kf) * 512;
        fragstride = 4 * 512;
    }
#pragma unroll
    for (int i = 0; i < 4; i++) {
        int row = (tid >> 5) + 8 * i, quad = tid & 31;
        f32x4 v = *(const f32x4*)(src + (size_t)row * rowstride + quad * 4);
        tile[row][quad * 4 + 0] = v.x; tile[row][quad * 4 + 1] = v.y;
        tile[row][quad * 4 + 2] = v.z; tile[row][quad * 4 + 3] = v.w;
    }
    __syncthreads();
    int w = tid >> 6, lane = tid & 63, lr = lane & 15, lq = lane >> 4;
#pragma unroll
    for (int ii = 0; ii < 2; ii++) {
        int hf = w * 2 + ii;
        bf16x8 o;
#pragma unroll
        for (int j = 0; j < 8; j++) {
            int kloc = (j < 4) ? (4 * lq + j) : (16 + 4 * lq + j - 4);
            o[j] = f2b(tile[kloc][hf * 16 + lr]);
        }
        *(bf16x8*)(dst + (size_t)hf * fragstride + lane * 8) = o;
    }
}

// ---- scatter: 16 blocks; deterministic positions from cnt16 (no atomics) ----
__global__ __launch_bounds__(256) void k_scatter(const int* __restrict__ task,
                                                 const int* __restrict__ cnt16g,
                                                 int* __restrict__ meta,
                                                 int* __restrict__ idxb) {
    __shared__ int c16s[16][9], tot[9], pre9[9], off[10], wv[4][9], sflag;
    int tid = threadIdx.x, lane = tid & 63, w = tid >> 6, blk = blockIdx.x;
    detect_i64(task, tid, &sflag);
    if (tid < 144) ((int*)c16s)[tid] = cnt16g[tid];
    __syncthreads();
    int f = sflag;
    int item = blk * 256 + tid;
    int tv = f ? task[2 * item] : task[item];
    int bk = (tv < 0) ? 8 : (tv > 7 ? 7 : tv);
    unsigned long long mymask = 0;
#pragma unroll
    for (int bu = 0; bu < 9; bu++) {
        unsigned long long m = __ballot(bk == bu);
        if (lane == 0) wv[w][bu] = (int)__popcll(m);
        if (bk == bu) mymask = m;
    }
    int rank = (int)__popcll(mymask & ((1ull << lane) - 1ull));
    __syncthreads();
    if (tid < 9) {
        int t = 0;
#pragma unroll
        for (int b = 0; b < 16; b++) t += c16s[b][tid];
        tot[tid] = t;
        int p = 0;
        for (int b = 0; b < blk; b++) p += c16s[b][tid];
        pre9[tid] = p;
        int s = 0;
#pragma unroll
        for (int ww = 0; ww < 4; ww++) { int q = wv[ww][tid]; wv[ww][tid] = s; s += q; }
    }
    __syncthreads();
    if (tid == 0) {
        int s = 0;
        for (int i = 0; i < 9; i++) { off[i] = s; s += (tot[i] + 31) & ~31; }
        off[9] = s;
    }
    __syncthreads();
    int pos = off[bk] + pre9[bk] + wv[w][bk] + rank;
    idxb[pos] = item;
    if (blk == 0) {
        if (tid < 9) meta[tid] = tot[tid];
        if (tid >= 16 && tid < 26) meta[tid] = off[tid - 16];
    }
}

// ---- GEMM1 fused: HbP[rt] = silu(x[g(r)][:] . Wd[t] + bd[t]) in A-frag layout ----
// grid = 8*256; t = bid&7 (XCD pin), tile = bid>>3 (16 rows each); 4 waves x 2 hf
__global__ __launch_bounds__(256) void k_gemm1(const float* __restrict__ x,
                                               const bf16_t* __restrict__ WdP,
                                               const float* __restrict__ bd,
                                               const int* __restrict__ idxb,
                                               const int* __restrict__ meta,
                                               bf16_t* __restrict__ HbP) {
    int bid = blockIdx.x;
    int t = bid & 7, tile = bid >> 3;
    int n = meta[t];
    int r0 = tile * 16;
    if (r0 >= n) return;
    int base = meta[16 + t];
    int tid = threadIdx.x, lane = tid & 63, w = tid >> 6;
    int lr = lane & 15, lq = lane >> 4;

    int br = r0 + lr;
    int g = idxb[base + (br < n ? br : n - 1)];
    const float* xrow = x + (size_t)g * SZ + 4 * lq;
    const bf16_t* wb = WdP + ((size_t)(t * 8 + w * 2) * 64) * 512 + lane * 8;

    f32x4 acc[2] = {};
#pragma unroll 8
    for (int kfi = 0; kfi < 64; kfi++) {
        f32x4 lo = *(const f32x4*)(xrow + kfi * 32);
        f32x4 hi = *(const f32x4*)(xrow + kfi * 32 + 16);
        bf16x8 a;
        a[0] = f2b(lo.x); a[1] = f2b(lo.y); a[2] = f2b(lo.z); a[3] = f2b(lo.w);
        a[4] = f2b(hi.x); a[5] = f2b(hi.y); a[6] = f2b(hi.z); a[7] = f2b(hi.w);
        bf16x8 b0 = *(const bf16x8*)(wb + (size_t)kfi * 512);
        bf16x8 b1 = *(const bf16x8*)(wb + (size_t)(64 + kfi) * 512);
        acc[0] = __builtin_amdgcn_mfma_f32_16x16x32_bf16(a, b0, acc[0], 0, 0, 0);
        acc[1] = __builtin_amdgcn_mfma_f32_16x16x32_bf16(a, b1, acc[1], 0, 0, 0);
    }

    // bias + silu, bounce through LDS (C-layout -> A-frag layout), +4 pad vs conflicts
    __shared__ bf16_t hl[16][132];
#pragma unroll
    for (int f = 0; f < 2; f++) {
        int h = w * 32 + f * 16 + lr;
        float bb = bd[t * HIDN + h];
#pragma unroll
        for (int reg = 0; reg < 4; reg++) {
            float v = acc[f][reg] + bb;
            hl[4 * lq + reg][h] = f2b(v / (1.f + __expf(-v)));
        }
    }
    __syncthreads();
    int rt = (base + r0) >> 4;
    bf16x8 o;
#pragma unroll
    for (int j = 0; j < 8; j++) {
        int k = w * 32 + ((j < 4) ? (4 * lq + j) : (16 + 4 * lq + j - 4));
        o[j] = hl[lr][k];
    }
    *(bf16x8*)(HbP + ((size_t)(rt * 4 + w) * 64 + lane) * 8) = o;
}

// ---- GEMM2 + residual + passthrough tail ----
// bid<8192: t = bid&7 (XCD pin), tile = (bid>>3)&127, cchunk = bid>>10
// bid>=8192: passthrough (bucket 8)
__global__ __launch_bounds__(256) void k_gemm2(const float* __restrict__ x,
                                               const bf16_t* __restrict__ WuP,
                                               const float* __restrict__ bu,
                                               const bf16_t* __restrict__ HbP,
                                               const int* __restrict__ idxb,
                                               const int* __restrict__ meta,
                                               float* __restrict__ out) {
    int bid = blockIdx.x;
    int tid = threadIdx.x;
    if (bid >= 8192) {
        int pb = bid - 8192;
        int n8 = meta[8];
        int tile = pb & 127, half = pb >> 7;
        int r0 = tile * 32;
        if (r0 >= n8) return;
        int base8 = meta[16 + 8];
        int row = tid >> 3, cq = tid & 7;
        int r = r0 + row;
        if (r < n8) {
            int g = idxb[base8 + r];
            const f32x4* xs = (const f32x4*)(x + (size_t)g * SZ + half * 256) + cq;
            f32x4* os = (f32x4*)(out + (size_t)g * SZ + half * 256) + cq;
#pragma unroll
            for (int j = 0; j < 8; j++) __builtin_nontemporal_store(xs[j * 8], &os[j * 8]);
        }
        return;
    }
    int t = bid & 7, tile = (bid >> 3) & 127, cchunk = bid >> 10;
    int n = meta[t];
    int r0 = tile * 32;
    if (r0 >= n) return;
    int base = meta[16 + t];
    int lane = tid & 63, w = tid >> 6;
    int wr = w & 1, wc = w >> 1, lr = lane & 15, lq = lane >> 4;

    int rt = (base + r0) / 16 + wr;           // base is 32-aligned
    const bf16_t* ap = HbP + (size_t)rt * 4 * 512 + lane * 8;
    bf16x8 a[4];
#pragma unroll
    for (int kf = 0; kf < 4; kf++) a[kf] = *(const bf16x8*)(ap + kf * 512);

    const bf16_t* bp = WuP + ((size_t)(t * 128 + cchunk * 16 + wc * 8) * 4) * 512 + lane * 8;
    f32x4 acc[8] = {};
#pragma unroll
    for (int cf = 0; cf < 8; cf++) {
#pragma unroll
        for (int kf = 0; kf < 4; kf++) {
            bf16x8 b = *(const bf16x8*)(bp + (size_t)(cf * 4 + kf) * 512);
            acc[cf] = __builtin_amdgcn_mfma_f32_16x16x32_bf16(a[kf], b, acc[cf], 0, 0, 0);
        }
    }

    int gr[4];
#pragma unroll
    for (int reg = 0; reg < 4; reg++) {
        int r = r0 + wr * 16 + 4 * lq + reg;
        gr[reg] = (r < n) ? idxb[base + r] : -1;
    }
#pragma unroll
    for (int cf = 0; cf < 8; cf++) {
        int c = cchunk * 256 + wc * 128 + cf * 16 + lr;
        float bb = bu[t * SZ + c];
#pragma unroll
        for (int reg = 0; reg < 4; reg++) {
            if (gr[reg] >= 0) {
                size_t o = (size_t)gr[reg] * SZ + c;
                __builtin_nontemporal_store(x[o] + acc[cf][reg] + bb, &out[o]);
            }
        }
    }
}

extern "C" void kernel_launch(void* const* d_in, const int* in_sizes, int n_in,
                              void* d_out, int out_size, void* d_ws, size_t ws_size,
                              hipStream_t stream) {
    const float* x  = (const float*)d_in[0];
    const float* Wd = (const float*)d_in[1];
    const float* bd = (const float*)d_in[2];
    const float* Wu = (const float*)d_in[3];
    const float* bu = (const float*)d_in[4];
    const int* task = (const int*)d_in[5];
    float* out = (float*)d_out;

    char* ws = (char*)d_ws;
    int* idxb    = (int*)ws;
    int* meta    = (int*)(ws + 17664);
    int* cnt16   = (int*)(ws + 17920);
    bf16_t* HbP  = (bf16_t*)(ws + 18560);
    bf16_t* WdP  = (bf16_t*)(ws + 1140864);
    bf16_t* WuP  = (bf16_t*)(ws + 5335168);

    k_prep<<<1040, 256, 0, stream>>>(Wd, Wu, task, WdP, WuP, cnt16);
    k_scatter<<<16, 256, 0, stream>>>(task, cnt16, meta, idxb);
    k_gemm1<<<8 * 256, 256, 0, stream>>>(x, WdP, bd, idxb, meta, HbP);
    k_gemm2<<<8192 + 1024, 256, 0, stream>>>(x, WuP, bu, HbP, idxb, meta, out);
}

// Round 9
// 81.833 us; speedup vs baseline: 1.1141x; 1.0059x over previous
//
#include <hip/hip_runtime.h>

#define BN 4096
#define SZ 2048
#define HIDN 128
#define NT 8
#define PADROWS 4384             // 4096 + 9*32 padding
#define PADTILES (PADROWS / 16)  // 274

typedef __bf16 bf16_t;
typedef bf16_t bf16x8 __attribute__((ext_vector_type(8)));
typedef float f32x4 __attribute__((ext_vector_type(4)));

__device__ inline bf16_t f2b(float f) {
    unsigned u = __builtin_bit_cast(unsigned, f);
    unsigned short s = (unsigned short)((u + 0x7fffu + ((u >> 16) & 1u)) >> 16);
    return __builtin_bit_cast(bf16_t, s);
}

// ws layout (bytes):
//   idxb  int[PADROWS] @0          (17536 B)
//   meta  int[64]      @17664      [0..8]=cnt, [16..25]=padded offs
//   cnt16 int[16*9]    @17920      per-hist-block bucket counts
//   HbP   bf16 frag    @18560      [rt(274)][kf(4)][lane(64)][8]  (~1.1 MB)
//   WdP   bf16 frag    @1140864    [t][hf(8)][kt(64)][lane][8]    (4 MB)
//   WuP   bf16 frag    @5335168    [t][cf(128)][kf(4)][lane][8]   (4 MB)

__device__ inline int detect_i64(const int* task, int tid, int* sflag) {
    // sample 64 odd words; int64 -> all are 0/-1 sign extensions
    if (tid < 64) {
        int v = task[2 * tid + 1];
        bool ok = (v == 0 || v == -1);
        unsigned long long m = __ballot(ok);
        if (tid == 0) *sflag = (m == ~0ull) ? 1 : 0;
    }
    return 0;
}

// ---- prep: blocks 0..1023 pack weights; blocks 1024..1039 histogram ----
__global__ __launch_bounds__(256) void k_prep(const float* __restrict__ Wd,
                                              const float* __restrict__ Wu,
                                              const int* __restrict__ task,
                                              bf16_t* __restrict__ WdP,
                                              bf16_t* __restrict__ WuP,
                                              int* __restrict__ cnt16g) {
    int bid = blockIdx.x, tid = threadIdx.x;
    __shared__ int wv[4][9], sflag;
    if (bid >= 1024) {  // ---- histogram: 16 blocks, 256 items each ----
        int blk = bid - 1024;
        int lane = tid & 63, w = tid >> 6;
        detect_i64(task, tid, &sflag);
        __syncthreads();
        int f = sflag;
        int item = blk * 256 + tid;
        int tv = f ? task[2 * item] : task[item];
        int bk = (tv < 0) ? 8 : (tv > 7 ? 7 : tv);
#pragma unroll
        for (int bu = 0; bu < 9; bu++) {
            unsigned long long m = __ballot(bk == bu);
            if (lane == 0) wv[w][bu] = (int)__popcll(m);
        }
        __syncthreads();
        if (tid < 9) {
            int s = 0;
#pragma unroll
            for (int ww = 0; ww < 4; ww++) s += wv[ww][tid];
            cnt16g[blk * 9 + tid] = s;
        }
        return;
    }
    // ---- weight pack (fp32 -> bf16 fragment layout) ----
    __shared__ float tile[32][132];
    const float* src;
    bf16_t* dst;
    int fragstride;
    size_t rowstride;
    if (bid < 512) {
        int t = bid >> 6, kt = bid & 63;
        src = Wd + ((size_t)t * SZ + kt * 32) * HIDN;
        rowstride = HIDN;
        dst = WdP + ((size_t)(t * 8) * 64 + kt) * 512;
        fragstride = 64 * 512;
    } else {
        int lb = bid - 512;
        int t = lb >> 6, rem = lb & 63;
        int kf = rem >> 4, cch = rem & 15;
        src = Wu + ((size_t)t * HIDN + kf * 32) * SZ + cch * 128;
        rowstride = SZ;
        dst = WuP + ((size_t)(t * 128 + cch * 8) * 4 + kf) * 512;
        fragstride = 4 * 512;
    }
#pragma unroll
    for (int i = 0; i < 4; i++) {
        int row = (tid >> 5) + 8 * i, quad = tid & 31;
        f32x4 v = *(const f32x4*)(src + (size_t)row * rowstride + quad * 4);
        tile[row][quad * 4 + 0] = v.x; tile[row][quad * 4 + 1] = v.y;
        tile[row][quad * 4 + 2] = v.z; tile[row][quad * 4 + 3] = v.w;
    }
    __syncthreads();
    int w = tid >> 6, lane = tid & 63, lr = lane & 15, lq = lane >> 4;
#pragma unroll
    for (int ii = 0; ii < 2; ii++) {
        int hf = w * 2 + ii;
        bf16x8 o;
#pragma unroll
        for (int j = 0; j < 8; j++) {
            int kloc = (j < 4) ? (4 * lq + j) : (16 + 4 * lq + j - 4);
            o[j] = f2b(tile[kloc][hf * 16 + lr]);
        }
        *(bf16x8*)(dst + (size_t)hf * fragstride + lane * 8) = o;
    }
}

// ---- scatter: 16 blocks; deterministic positions from cnt16 (no atomics) ----
__global__ __launch_bounds__(256) void k_scatter(const int* __restrict__ task,
                                                 const int* __restrict__ cnt16g,
                                                 int* __restrict__ meta,
                                                 int* __restrict__ idxb) {
    __shared__ int c16s[16][9], tot[9], pre9[9], off[10], wv[4][9], sflag;
    int tid = threadIdx.x, lane = tid & 63, w = tid >> 6, blk = blockIdx.x;
    detect_i64(task, tid, &sflag);
    if (tid < 144) ((int*)c16s)[tid] = cnt16g[tid];
    __syncthreads();
    int f = sflag;
    int item = blk * 256 + tid;
    int tv = f ? task[2 * item] : task[item];
    int bk = (tv < 0) ? 8 : (tv > 7 ? 7 : tv);
    unsigned long long mymask = 0;
#pragma unroll
    for (int bu = 0; bu < 9; bu++) {
        unsigned long long m = __ballot(bk == bu);
        if (lane == 0) wv[w][bu] = (int)__popcll(m);
        if (bk == bu) mymask = m;
    }
    int rank = (int)__popcll(mymask & ((1ull << lane) - 1ull));
    __syncthreads();
    if (tid < 9) {
        int t = 0;
#pragma unroll
        for (int b = 0; b < 16; b++) t += c16s[b][tid];
        tot[tid] = t;
        int p = 0;
        for (int b = 0; b < blk; b++) p += c16s[b][tid];
        pre9[tid] = p;
        int s = 0;
#pragma unroll
        for (int ww = 0; ww < 4; ww++) { int q = wv[ww][tid]; wv[ww][tid] = s; s += q; }
    }
    __syncthreads();
    if (tid == 0) {
        int s = 0;
        for (int i = 0; i < 9; i++) { off[i] = s; s += (tot[i] + 31) & ~31; }
        off[9] = s;
    }
    __syncthreads();
    int pos = off[bk] + pre9[bk] + wv[w][bk] + rank;
    idxb[pos] = item;
    if (blk == 0) {
        if (tid < 9) meta[tid] = tot[tid];
        if (tid >= 16 && tid < 26) meta[tid] = off[tid - 16];
    }
}

// ---- GEMM1 fused, intra-block split-K: 1024 thr = 4 K-groups x 4 h-waves ----
// t = bid&7 (XCD pin), tile = bid>>3 (16 rows); HbP out in A-frag layout
__global__ __launch_bounds__(1024) void k_gemm1(const float* __restrict__ x,
                                                const bf16_t* __restrict__ WdP,
                                                const float* __restrict__ bd,
                                                const int* __restrict__ idxb,
                                                const int* __restrict__ meta,
                                                bf16_t* __restrict__ HbP) {
    int bid = blockIdx.x;
    int t = bid & 7, tile = bid >> 3;
    int n = meta[t];
    int r0 = tile * 16;
    if (r0 >= n) return;
    int base = meta[16 + t];
    int tid = threadIdx.x, lane = tid & 63, w16 = tid >> 6;
    int w = w16 & 3;      // h-wave: hf pair w*2, w*2+1
    int kg = w16 >> 2;    // K-group: k in [kg*512, kg*512+512)
    int lr = lane & 15, lq = lane >> 4;

    int br = r0 + lr;
    int g = idxb[base + (br < n ? br : n - 1)];
    const float* xrow = x + (size_t)g * SZ + kg * 512 + 4 * lq;
    const bf16_t* wb = WdP + ((size_t)(t * 8 + w * 2) * 64 + kg * 16) * 512 + lane * 8;

    f32x4 acc[2] = {};
#pragma unroll 4
    for (int kfi = 0; kfi < 16; kfi++) {
        f32x4 lo = *(const f32x4*)(xrow + kfi * 32);
        f32x4 hi = *(const f32x4*)(xrow + kfi * 32 + 16);
        bf16x8 a;
        a[0] = f2b(lo.x); a[1] = f2b(lo.y); a[2] = f2b(lo.z); a[3] = f2b(lo.w);
        a[4] = f2b(hi.x); a[5] = f2b(hi.y); a[6] = f2b(hi.z); a[7] = f2b(hi.w);
        bf16x8 b0 = *(const bf16x8*)(wb + (size_t)kfi * 512);
        bf16x8 b1 = *(const bf16x8*)(wb + (size_t)(64 + kfi) * 512);
        acc[0] = __builtin_amdgcn_mfma_f32_16x16x32_bf16(a, b0, acc[0], 0, 0, 0);
        acc[1] = __builtin_amdgcn_mfma_f32_16x16x32_bf16(a, b1, acc[1], 0, 0, 0);
    }

    __shared__ float red[3][16][132];  // partials from kg=1..3 (132 pad: 2-way max)
    __shared__ bf16_t hl[16][132];
    if (kg > 0) {
#pragma unroll
        for (int f = 0; f < 2; f++) {
            int h = w * 32 + f * 16 + lr;
#pragma unroll
            for (int reg = 0; reg < 4; reg++)
                red[kg - 1][4 * lq + reg][h] = acc[f][reg];
        }
    }
    __syncthreads();
    if (kg == 0) {
        // reduce + bias + silu -> hl (C-layout -> A-frag via LDS bounce)
#pragma unroll
        for (int f = 0; f < 2; f++) {
            int h = w * 32 + f * 16 + lr;
            float bb = bd[t * HIDN + h];
#pragma unroll
            for (int reg = 0; reg < 4; reg++) {
                int row = 4 * lq + reg;
                float v = acc[f][reg] + red[0][row][h] + red[1][row][h] +
                          red[2][row][h] + bb;
                hl[row][h] = f2b(v / (1.f + __expf(-v)));
            }
        }
    }
    __syncthreads();
    if (kg == 0) {
        int rt = (base + r0) >> 4;
        bf16x8 o;
#pragma unroll
        for (int j = 0; j < 8; j++) {
            int k = w * 32 + ((j < 4) ? (4 * lq + j) : (16 + 4 * lq + j - 4));
            o[j] = hl[lr][k];
        }
        *(bf16x8*)(HbP + ((size_t)(rt * 4 + w) * 64 + lane) * 8) = o;
    }
}

// ---- GEMM2 + residual + passthrough tail ----
// bid<8192: t = bid&7 (XCD pin), tile = (bid>>3)&127, cchunk = bid>>10
// bid>=8192: passthrough (bucket 8)
__global__ __launch_bounds__(256) void k_gemm2(const float* __restrict__ x,
                                               const bf16_t* __restrict__ WuP,
                                               const float* __restrict__ bu,
                                               const bf16_t* __restrict__ HbP,
                                               const int* __restrict__ idxb,
                                               const int* __restrict__ meta,
                                               float* __restrict__ out) {
    int bid = blockIdx.x;
    int tid = threadIdx.x;
    if (bid >= 8192) {
        int pb = bid - 8192;
        int n8 = meta[8];
        int tile = pb & 127, half = pb >> 7;
        int r0 = tile * 32;
        if (r0 >= n8) return;
        int base8 = meta[16 + 8];
        int row = tid >> 3, cq = tid & 7;
        int r = r0 + row;
        if (r < n8) {
            int g = idxb[base8 + r];
            const f32x4* xs = (const f32x4*)(x + (size_t)g * SZ + half * 256) + cq;
            f32x4* os = (f32x4*)(out + (size_t)g * SZ + half * 256) + cq;
#pragma unroll
            for (int j = 0; j < 8; j++) __builtin_nontemporal_store(xs[j * 8], &os[j * 8]);
        }
        return;
    }
    int t = bid & 7, tile = (bid >> 3) & 127, cchunk = bid >> 10;
    int n = meta[t];
    int r0 = tile * 32;
    if (r0 >= n) return;
    int base = meta[16 + t];
    int lane = tid & 63, w = tid >> 6;
    int wr = w & 1, wc = w >> 1, lr = lane & 15, lq = lane >> 4;

    int rt = (base + r0) / 16 + wr;           // base is 32-aligned
    const bf16_t* ap = HbP + (size_t)rt * 4 * 512 + lane * 8;
    bf16x8 a[4];
#pragma unroll
    for (int kf = 0; kf < 4; kf++) a[kf] = *(const bf16x8*)(ap + kf * 512);

    const bf16_t* bp = WuP + ((size_t)(t * 128 + cchunk * 16 + wc * 8) * 4) * 512 + lane * 8;
    f32x4 acc[8] = {};
#pragma unroll
    for (int cf = 0; cf < 8; cf++) {
#pragma unroll
        for (int kf = 0; kf < 4; kf++) {
            bf16x8 b = *(const bf16x8*)(bp + (size_t)(cf * 4 + kf) * 512);
            acc[cf] = __builtin_amdgcn_mfma_f32_16x16x32_bf16(a[kf], b, acc[cf], 0, 0, 0);
        }
    }

    int gr[4];
#pragma unroll
    for (int reg = 0; reg < 4; reg++) {
        int r = r0 + wr * 16 + 4 * lq + reg;
        gr[reg] = (r < n) ? idxb[base + r] : -1;
    }
#pragma unroll
    for (int cf = 0; cf < 8; cf++) {
        int c = cchunk * 256 + wc * 128 + cf * 16 + lr;
        float bb = bu[t * SZ + c];
#pragma unroll
        for (int reg = 0; reg < 4; reg++) {
            if (gr[reg] >= 0) {
                size_t o = (size_t)gr[reg] * SZ + c;
                __builtin_nontemporal_store(x[o] + acc[cf][reg] + bb, &out[o]);
            }
        }
    }
}

extern "C" void kernel_launch(void* const* d_in, const int* in_sizes, int n_in,
                              void* d_out, int out_size, void* d_ws, size_t ws_size,
                              hipStream_t stream) {
    const float* x  = (const float*)d_in[0];
    const float* Wd = (const float*)d_in[1];
    const float* bd = (const float*)d_in[2];
    const float* Wu = (const float*)d_in[3];
    const float* bu = (const float*)d_in[4];
    const int* task = (const int*)d_in[5];
    float* out = (float*)d_out;

    char* ws = (char*)d_ws;
    int* idxb    = (int*)ws;
    int* meta    = (int*)(ws + 17664);
    int* cnt16   = (int*)(ws + 17920);
    bf16_t* HbP  = (bf16_t*)(ws + 18560);
    bf16_t* WdP  = (bf16_t*)(ws + 1140864);
    bf16_t* WuP  = (bf16_t*)(ws + 5335168);

    k_prep<<<1040, 256, 0, stream>>>(Wd, Wu, task, WdP, WuP, cnt16);
    k_scatter<<<16, 256, 0, stream>>>(task, cnt16, meta, idxb);
    k_gemm1<<<8 * 256, 1024, 0, stream>>>(x, WdP, bd, idxb, meta, HbP);
    k_gemm2<<<8192 + 1024, 256, 0, stream>>>(x, WuP, bu, HbP, idxb, meta, out);
}

// Round 10
// 60.586 us; speedup vs baseline: 1.5048x; 1.3507x over previous
//
#include <hip/hip_runtime.h>

#define BN 4096
#define SZ 2048
#define HIDN 128
#define NT 8
#define PADROWS 4384             // 4096 + 9*32 padding
#define PADTILES (PADROWS / 16)  // 274

typedef __bf16 bf16_t;
typedef bf16_t bf16x4 __attribute__((ext_vector_type(4)));
typedef bf16_t bf16x8 __attribute__((ext_vector_type(8)));
typedef float f32x4 __attribute__((ext_vector_type(4)));

__device__ inline bf16_t f2b(float f) {
    unsigned u = __builtin_bit_cast(unsigned, f);
    unsigned short s = (unsigned short)((u + 0x7fffu + ((u >> 16) & 1u)) >> 16);
    return __builtin_bit_cast(bf16_t, s);
}

// ws layout (bytes):
//   idxb  int[PADROWS] @0          (17536 B)
//   meta  int[64]      @17664      [0..8]=cnt, [16..25]=padded offs
//   cnt16 int[16*9]    @17920      per-hist-block bucket counts
//   HbP   bf16 frag    @18560      [rt(274)][kf(4)][lane(64)][8]  (~1.1 MB)
//   WdP   bf16 frag    @1140864    [t][hf(8)][kt(64)][lane][8]    (4 MB)
//   WuP   bf16 frag    @5335168    [t][cf(128)][kf(4)][lane][8]   (4 MB)

__device__ inline int detect_i64(const int* task, int tid, int* sflag) {
    // sample 64 odd words; int64 -> all are 0/-1 sign extensions
    if (tid < 64) {
        int v = task[2 * tid + 1];
        bool ok = (v == 0 || v == -1);
        unsigned long long m = __ballot(ok);
        if (tid == 0) *sflag = (m == ~0ull) ? 1 : 0;
    }
    return 0;
}

// ---- prep: blocks 0..1023 pack weights; blocks 1024..1039 histogram ----
__global__ __launch_bounds__(256) void k_prep(const float* __restrict__ Wd,
                                              const float* __restrict__ Wu,
                                              const int* __restrict__ task,
                                              bf16_t* __restrict__ WdP,
                                              bf16_t* __restrict__ WuP,
                                              int* __restrict__ cnt16g) {
    int bid = blockIdx.x, tid = threadIdx.x;
    __shared__ int wv[4][9], sflag;
    if (bid >= 1024) {  // ---- histogram: 16 blocks, 256 items each ----
        int blk = bid - 1024;
        int lane = tid & 63, w = tid >> 6;
        detect_i64(task, tid, &sflag);
        __syncthreads();
        int f = sflag;
        int item = blk * 256 + tid;
        int tv = f ? task[2 * item] : task[item];
        int bk = (tv < 0) ? 8 : (tv > 7 ? 7 : tv);
#pragma unroll
        for (int bu = 0; bu < 9; bu++) {
            unsigned long long m = __ballot(bk == bu);
            if (lane == 0) wv[w][bu] = (int)__popcll(m);
        }
        __syncthreads();
        if (tid < 9) {
            int s = 0;
#pragma unroll
            for (int ww = 0; ww < 4; ww++) s += wv[ww][tid];
            cnt16g[blk * 9 + tid] = s;
        }
        return;
    }
    // ---- weight pack (fp32 -> bf16 fragment layout) ----
    __shared__ float tile[32][132];
    const float* src;
    bf16_t* dst;
    int fragstride;
    size_t rowstride;
    if (bid < 512) {
        int t = bid >> 6, kt = bid & 63;
        src = Wd + ((size_t)t * SZ + kt * 32) * HIDN;
        rowstride = HIDN;
        dst = WdP + ((size_t)(t * 8) * 64 + kt) * 512;
        fragstride = 64 * 512;
    } else {
        int lb = bid - 512;
        int t = lb >> 6, rem = lb & 63;
        int kf = rem >> 4, cch = rem & 15;
        src = Wu + ((size_t)t * HIDN + kf * 32) * SZ + cch * 128;
        rowstride = SZ;
        dst = WuP + ((size_t)(t * 128 + cch * 8) * 4 + kf) * 512;
        fragstride = 4 * 512;
    }
#pragma unroll
    for (int i = 0; i < 4; i++) {
        int row = (tid >> 5) + 8 * i, quad = tid & 31;
        f32x4 v = *(const f32x4*)(src + (size_t)row * rowstride + quad * 4);
        tile[row][quad * 4 + 0] = v.x; tile[row][quad * 4 + 1] = v.y;
        tile[row][quad * 4 + 2] = v.z; tile[row][quad * 4 + 3] = v.w;
    }
    __syncthreads();
    int w = tid >> 6, lane = tid & 63, lr = lane & 15, lq = lane >> 4;
#pragma unroll
    for (int ii = 0; ii < 2; ii++) {
        int hf = w * 2 + ii;
        bf16x8 o;
#pragma unroll
        for (int j = 0; j < 8; j++) {
            int kloc = (j < 4) ? (4 * lq + j) : (16 + 4 * lq + j - 4);
            o[j] = f2b(tile[kloc][hf * 16 + lr]);
        }
        *(bf16x8*)(dst + (size_t)hf * fragstride + lane * 8) = o;
    }
}

// ---- scatter: 16 blocks; deterministic positions from cnt16 (no atomics) ----
__global__ __launch_bounds__(256) void k_scatter(const int* __restrict__ task,
                                                 const int* __restrict__ cnt16g,
                                                 int* __restrict__ meta,
                                                 int* __restrict__ idxb) {
    __shared__ int c16s[16][9], tot[9], pre9[9], off[10], wv[4][9], sflag;
    int tid = threadIdx.x, lane = tid & 63, w = tid >> 6, blk = blockIdx.x;
    detect_i64(task, tid, &sflag);
    if (tid < 144) ((int*)c16s)[tid] = cnt16g[tid];
    __syncthreads();
    int f = sflag;
    int item = blk * 256 + tid;
    int tv = f ? task[2 * item] : task[item];
    int bk = (tv < 0) ? 8 : (tv > 7 ? 7 : tv);
    unsigned long long mymask = 0;
#pragma unroll
    for (int bu = 0; bu < 9; bu++) {
        unsigned long long m = __ballot(bk == bu);
        if (lane == 0) wv[w][bu] = (int)__popcll(m);
        if (bk == bu) mymask = m;
    }
    int rank = (int)__popcll(mymask & ((1ull << lane) - 1ull));
    __syncthreads();
    if (tid < 9) {
        int t = 0;
#pragma unroll
        for (int b = 0; b < 16; b++) t += c16s[b][tid];
        tot[tid] = t;
        int p = 0;
        for (int b = 0; b < blk; b++) p += c16s[b][tid];
        pre9[tid] = p;
        int s = 0;
#pragma unroll
        for (int ww = 0; ww < 4; ww++) { int q = wv[ww][tid]; wv[ww][tid] = s; s += q; }
    }
    __syncthreads();
    if (tid == 0) {
        int s = 0;
        for (int i = 0; i < 9; i++) { off[i] = s; s += (tot[i] + 31) & ~31; }
        off[9] = s;
    }
    __syncthreads();
    int pos = off[bk] + pre9[bk] + wv[w][bk] + rank;
    idxb[pos] = item;
    if (blk == 0) {
        if (tid < 9) meta[tid] = tot[tid];
        if (tid >= 16 && tid < 26) meta[tid] = off[tid - 16];
    }
}

// ---- GEMM1 fused, LDS-staged x: coalesced row loads, double-buffered K-chunks ----
// t = bid&7 (XCD pin), tile = bid>>3 (16 rows); 4 waves x 2 hf; HbP out (A-frag)
__global__ __launch_bounds__(256) void k_gemm1(const float* __restrict__ x,
                                               const bf16_t* __restrict__ WdP,
                                               const float* __restrict__ bd,
                                               const int* __restrict__ idxb,
                                               const int* __restrict__ meta,
                                               bf16_t* __restrict__ HbP) {
    int bid = blockIdx.x;
    int t = bid & 7, tile = bid >> 3;
    int n = meta[t];
    int r0 = tile * 16;
    if (r0 >= n) return;
    int base = meta[16 + t];
    int tid = threadIdx.x, lane = tid & 63, w = tid >> 6;
    int lr = lane & 15, lq = lane >> 4;

    __shared__ int sg[16];
    __shared__ bf16_t xl[2][16][260];   // stride 260: 8B-aligned rows, <=2-way conflicts
    __shared__ bf16_t hl[16][132];
    if (tid < 16) {
        int r = r0 + tid;
        sg[tid] = idxb[base + (r < n ? r : n - 1)];
    }
    __syncthreads();

    // stage chunk 0: wave w loads rows 4w..4w+3, 256 f32 each, fully coalesced
    f32x4 pre[4];
#pragma unroll
    for (int rr = 0; rr < 4; rr++)
        pre[rr] = *(const f32x4*)(x + (size_t)sg[w * 4 + rr] * SZ + lane * 4);
#pragma unroll
    for (int rr = 0; rr < 4; rr++) {
        bf16x4 v = {f2b(pre[rr].x), f2b(pre[rr].y), f2b(pre[rr].z), f2b(pre[rr].w)};
        *(bf16x4*)(&xl[0][w * 4 + rr][lane * 4]) = v;
    }
    __syncthreads();

    const bf16_t* wb = WdP + ((size_t)(t * 8 + w * 2) * 64) * 512 + lane * 8;
    f32x4 acc[2] = {};
    for (int c = 0; c < 8; c++) {
        int cur = c & 1;
        if (c < 7) {  // issue next chunk's global loads early (hide under MFMA)
#pragma unroll
            for (int rr = 0; rr < 4; rr++)
                pre[rr] = *(const f32x4*)(x + (size_t)sg[w * 4 + rr] * SZ +
                                          (c + 1) * 256 + lane * 4);
        }
#pragma unroll
        for (int k8 = 0; k8 < 8; k8++) {
            int kf = c * 8 + k8;
            bf16x4 alo = *(const bf16x4*)(&xl[cur][lr][k8 * 32 + 4 * lq]);
            bf16x4 ahi = *(const bf16x4*)(&xl[cur][lr][k8 * 32 + 16 + 4 * lq]);
            bf16x8 a;
            a[0] = alo[0]; a[1] = alo[1]; a[2] = alo[2]; a[3] = alo[3];
            a[4] = ahi[0]; a[5] = ahi[1]; a[6] = ahi[2]; a[7] = ahi[3];
            bf16x8 b0 = *(const bf16x8*)(wb + (size_t)kf * 512);
            bf16x8 b1 = *(const bf16x8*)(wb + (size_t)(64 + kf) * 512);
            acc[0] = __builtin_amdgcn_mfma_f32_16x16x32_bf16(a, b0, acc[0], 0, 0, 0);
            acc[1] = __builtin_amdgcn_mfma_f32_16x16x32_bf16(a, b1, acc[1], 0, 0, 0);
        }
        if (c < 7) {  // write next chunk into the other buffer
#pragma unroll
            for (int rr = 0; rr < 4; rr++) {
                bf16x4 v = {f2b(pre[rr].x), f2b(pre[rr].y), f2b(pre[rr].z), f2b(pre[rr].w)};
                *(bf16x4*)(&xl[cur ^ 1][w * 4 + rr][lane * 4]) = v;
            }
        }
        __syncthreads();
    }

    // bias + silu, bounce through LDS (C-layout -> A-frag layout)
#pragma unroll
    for (int f = 0; f < 2; f++) {
        int h = w * 32 + f * 16 + lr;
        float bb = bd[t * HIDN + h];
#pragma unroll
        for (int reg = 0; reg < 4; reg++) {
            float v = acc[f][reg] + bb;
            hl[4 * lq + reg][h] = f2b(v / (1.f + __expf(-v)));
        }
    }
    __syncthreads();
    int rt = (base + r0) >> 4;
    bf16x8 o;
#pragma unroll
    for (int j = 0; j < 8; j++) {
        int k = w * 32 + ((j < 4) ? (4 * lq + j) : (16 + 4 * lq + j - 4));
        o[j] = hl[lr][k];
    }
    *(bf16x8*)(HbP + ((size_t)(rt * 4 + w) * 64 + lane) * 8) = o;
}

// ---- GEMM2 + residual + passthrough tail ----
// bid<8192: t = bid&7 (XCD pin), tile = (bid>>3)&127, cchunk = bid>>10
// bid>=8192: passthrough (bucket 8)
__global__ __launch_bounds__(256) void k_gemm2(const float* __restrict__ x,
                                               const bf16_t* __restrict__ WuP,
                                               const float* __restrict__ bu,
                                               const bf16_t* __restrict__ HbP,
                                               const int* __restrict__ idxb,
                                               const int* __restrict__ meta,
                                               float* __restrict__ out) {
    int bid = blockIdx.x;
    int tid = threadIdx.x;
    if (bid >= 8192) {
        int pb = bid - 8192;
        int n8 = meta[8];
        int tile = pb & 127, half = pb >> 7;
        int r0 = tile * 32;
        if (r0 >= n8) return;
        int base8 = meta[16 + 8];
        int row = tid >> 3, cq = tid & 7;
        int r = r0 + row;
        if (r < n8) {
            int g = idxb[base8 + r];
            const f32x4* xs = (const f32x4*)(x + (size_t)g * SZ + half * 256) + cq;
            f32x4* os = (f32x4*)(out + (size_t)g * SZ + half * 256) + cq;
#pragma unroll
            for (int j = 0; j < 8; j++) __builtin_nontemporal_store(xs[j * 8], &os[j * 8]);
        }
        return;
    }
    int t = bid & 7, tile = (bid >> 3) & 127, cchunk = bid >> 10;
    int n = meta[t];
    int r0 = tile * 32;
    if (r0 >= n) return;
    int base = meta[16 + t];
    int lane = tid & 63, w = tid >> 6;
    int wr = w & 1, wc = w >> 1, lr = lane & 15, lq = lane >> 4;

    int rt = (base + r0) / 16 + wr;           // base is 32-aligned
    const bf16_t* ap = HbP + (size_t)rt * 4 * 512 + lane * 8;
    bf16x8 a[4];
#pragma unroll
    for (int kf = 0; kf < 4; kf++) a[kf] = *(const bf16x8*)(ap + kf * 512);

    const bf16_t* bp = WuP + ((size_t)(t * 128 + cchunk * 16 + wc * 8) * 4) * 512 + lane * 8;
    f32x4 acc[8] = {};
#pragma unroll
    for (int cf = 0; cf < 8; cf++) {
#pragma unroll
        for (int kf = 0; kf < 4; kf++) {
            bf16x8 b = *(const bf16x8*)(bp + (size_t)(cf * 4 + kf) * 512);
            acc[cf] = __builtin_amdgcn_mfma_f32_16x16x32_bf16(a[kf], b, acc[cf], 0, 0, 0);
        }
    }

    int gr[4];
#pragma unroll
    for (int reg = 0; reg < 4; reg++) {
        int r = r0 + wr * 16 + 4 * lq + reg;
        gr[reg] = (r < n) ? idxb[base + r] : -1;
    }
#pragma unroll
    for (int cf = 0; cf < 8; cf++) {
        int c = cchunk * 256 + wc * 128 + cf * 16 + lr;
        float bb = bu[t * SZ + c];
#pragma unroll
        for (int reg = 0; reg < 4; reg++) {
            if (gr[reg] >= 0) {
                size_t o = (size_t)gr[reg] * SZ + c;
                __builtin_nontemporal_store(x[o] + acc[cf][reg] + bb, &out[o]);
            }
        }
    }
}

extern "C" void kernel_launch(void* const* d_in, const int* in_sizes, int n_in,
                              void* d_out, int out_size, void* d_ws, size_t ws_size,
                              hipStream_t stream) {
    const float* x  = (const float*)d_in[0];
    const float* Wd = (const float*)d_in[1];
    const float* bd = (const float*)d_in[2];
    const float* Wu = (const float*)d_in[3];
    const float* bu = (const float*)d_in[4];
    const int* task = (const int*)d_in[5];
    float* out = (float*)d_out;

    char* ws = (char*)d_ws;
    int* idxb    = (int*)ws;
    int* meta    = (int*)(ws + 17664);
    int* cnt16   = (int*)(ws + 17920);
    bf16_t* HbP  = (bf16_t*)(ws + 18560);
    bf16_t* WdP  = (bf16_t*)(ws + 1140864);
    bf16_t* WuP  = (bf16_t*)(ws + 5335168);

    k_prep<<<1040, 256, 0, stream>>>(Wd, Wu, task, WdP, WuP, cnt16);
    k_scatter<<<16, 256, 0, stream>>>(task, cnt16, meta, idxb);
    k_gemm1<<<8 * 256, 256, 0, stream>>>(x, WdP, bd, idxb, meta, HbP);
    k_gemm2<<<8192 + 1024, 256, 0, stream>>>(x, WuP, bu, HbP, idxb, meta, out);
}

// Round 11
// 48.726 us; speedup vs baseline: 1.8710x; 1.2434x over previous
//
#include <hip/hip_runtime.h>

#define BN 4096
#define SZ 2048
#define HIDN 128
#define NT 8
#define PADROWS 4384             // 4096 + 9*32 padding
#define PADTILES (PADROWS / 16)  // 274

typedef __bf16 bf16_t;
typedef bf16_t bf16x4 __attribute__((ext_vector_type(4)));
typedef bf16_t bf16x8 __attribute__((ext_vector_type(8)));
typedef float f32x4 __attribute__((ext_vector_type(4)));

__device__ inline bf16_t f2b(float f) {
    unsigned u = __builtin_bit_cast(unsigned, f);
    unsigned short s = (unsigned short)((u + 0x7fffu + ((u >> 16) & 1u)) >> 16);
    return __builtin_bit_cast(bf16_t, s);
}

// ws layout (bytes):
//   idxb  int[PADROWS] @0          (17536 B)
//   meta  int[64]      @17664      [0..8]=cnt, [16..25]=padded offs
//   cnt16 int[16*9]    @17920      per-hist-block bucket counts
//   HbP   bf16 frag    @18560      [rt(274)][kf(4)][lane(64)][8]  (~1.1 MB)
//   WdP   bf16 frag    @1140864    [t][hf(8)][kt(64)][lane][8]    (4 MB)
//   WuP   bf16 frag    @5335168    [t][cf(128)][kf(4)][lane][8]   (4 MB)

__device__ inline int detect_i64(const int* task, int tid, int* sflag) {
    // sample 64 odd words; int64 -> all are 0/-1 sign extensions
    if (tid < 64) {
        int v = task[2 * tid + 1];
        bool ok = (v == 0 || v == -1);
        unsigned long long m = __ballot(ok);
        if (tid == 0) *sflag = (m == ~0ull) ? 1 : 0;
    }
    return 0;
}

// ---- prep: blocks 0..511 pack Wd; blocks 512..527 histogram ----
__global__ __launch_bounds__(256) void k_prep(const float* __restrict__ Wd,
                                              const int* __restrict__ task,
                                              bf16_t* __restrict__ WdP,
                                              int* __restrict__ cnt16g) {
    int bid = blockIdx.x, tid = threadIdx.x;
    __shared__ int wv[4][9], sflag;
    if (bid >= 512) {  // ---- histogram: 16 blocks, 256 items each ----
        int blk = bid - 512;
        int lane = tid & 63, w = tid >> 6;
        detect_i64(task, tid, &sflag);
        __syncthreads();
        int f = sflag;
        int item = blk * 256 + tid;
        int tv = f ? task[2 * item] : task[item];
        int bk = (tv < 0) ? 8 : (tv > 7 ? 7 : tv);
#pragma unroll
        for (int bu = 0; bu < 9; bu++) {
            unsigned long long m = __ballot(bk == bu);
            if (lane == 0) wv[w][bu] = (int)__popcll(m);
        }
        __syncthreads();
        if (tid < 9) {
            int s = 0;
#pragma unroll
            for (int ww = 0; ww < 4; ww++) s += wv[ww][tid];
            cnt16g[blk * 9 + tid] = s;
        }
        return;
    }
    // ---- Wd pack (fp32 -> bf16 fragment layout) ----
    __shared__ float tile[32][132];
    int t = bid >> 6, kt = bid & 63;
    const float* src = Wd + ((size_t)t * SZ + kt * 32) * HIDN;
    bf16_t* dst = WdP + ((size_t)(t * 8) * 64 + kt) * 512;
#pragma unroll
    for (int i = 0; i < 4; i++) {
        int row = (tid >> 5) + 8 * i, quad = tid & 31;
        f32x4 v = *(const f32x4*)(src + (size_t)row * HIDN + quad * 4);
        tile[row][quad * 4 + 0] = v.x; tile[row][quad * 4 + 1] = v.y;
        tile[row][quad * 4 + 2] = v.z; tile[row][quad * 4 + 3] = v.w;
    }
    __syncthreads();
    int w = tid >> 6, lane = tid & 63, lr = lane & 15, lq = lane >> 4;
#pragma unroll
    for (int ii = 0; ii < 2; ii++) {
        int hf = w * 2 + ii;
        bf16x8 o;
#pragma unroll
        for (int j = 0; j < 8; j++) {
            int kloc = (j < 4) ? (4 * lq + j) : (16 + 4 * lq + j - 4);
            o[j] = f2b(tile[kloc][hf * 16 + lr]);
        }
        *(bf16x8*)(dst + (size_t)hf * 64 * 512 + lane * 8) = o;
    }
}

// ---- scatter: 16 blocks; deterministic positions from cnt16 (no atomics) ----
__global__ __launch_bounds__(256) void k_scatter(const int* __restrict__ task,
                                                 const int* __restrict__ cnt16g,
                                                 int* __restrict__ meta,
                                                 int* __restrict__ idxb) {
    __shared__ int c16s[16][9], tot[9], pre9[9], off[10], wv[4][9], sflag;
    int tid = threadIdx.x, lane = tid & 63, w = tid >> 6, blk = blockIdx.x;
    detect_i64(task, tid, &sflag);
    if (tid < 144) ((int*)c16s)[tid] = cnt16g[tid];
    __syncthreads();
    int f = sflag;
    int item = blk * 256 + tid;
    int tv = f ? task[2 * item] : task[item];
    int bk = (tv < 0) ? 8 : (tv > 7 ? 7 : tv);
    unsigned long long mymask = 0;
#pragma unroll
    for (int bu = 0; bu < 9; bu++) {
        unsigned long long m = __ballot(bk == bu);
        if (lane == 0) wv[w][bu] = (int)__popcll(m);
        if (bk == bu) mymask = m;
    }
    int rank = (int)__popcll(mymask & ((1ull << lane) - 1ull));
    __syncthreads();
    if (tid < 9) {
        int t = 0;
#pragma unroll
        for (int b = 0; b < 16; b++) t += c16s[b][tid];
        tot[tid] = t;
        int p = 0;
        for (int b = 0; b < blk; b++) p += c16s[b][tid];
        pre9[tid] = p;
        int s = 0;
#pragma unroll
        for (int ww = 0; ww < 4; ww++) { int q = wv[ww][tid]; wv[ww][tid] = s; s += q; }
    }
    __syncthreads();
    if (tid == 0) {
        int s = 0;
        for (int i = 0; i < 9; i++) { off[i] = s; s += (tot[i] + 31) & ~31; }
        off[9] = s;
    }
    __syncthreads();
    int pos = off[bk] + pre9[bk] + wv[w][bk] + rank;
    idxb[pos] = item;
    if (blk == 0) {
        if (tid < 9) meta[tid] = tot[tid];
        if (tid >= 16 && tid < 26) meta[tid] = off[tid - 16];
    }
}

// ---- GEMM1 fused (h-split x2) + Wu-pack tail ----
// bid<4096: t = bid&7, hh = (bid>>3)&1 (64-h half), tile = bid>>4 (16 rows)
//   4 waves x 1 hf each; x LDS-staged coalesced, double-buffered; HbP A-frag out
// bid>=4096: Wu pack (512 blocks) runs concurrently on idle CUs
__global__ __launch_bounds__(256) void k_gemm1(const float* __restrict__ x,
                                               const float* __restrict__ Wu,
                                               const bf16_t* __restrict__ WdP,
                                               bf16_t* __restrict__ WuP,
                                               const float* __restrict__ bd,
                                               const int* __restrict__ idxb,
                                               const int* __restrict__ meta,
                                               bf16_t* __restrict__ HbP) {
    int bid = blockIdx.x;
    int tid = threadIdx.x, lane = tid & 63, w = tid >> 6;
    int lr = lane & 15, lq = lane >> 4;
    if (bid >= 4096) {  // ---- Wu pack ----
        __shared__ float tile[32][132];
        int lb = bid - 4096;
        int t = lb >> 6, rem = lb & 63;
        int kf = rem >> 4, cch = rem & 15;
        const float* src = Wu + ((size_t)t * HIDN + kf * 32) * SZ + cch * 128;
        bf16_t* dst = WuP + ((size_t)(t * 128 + cch * 8) * 4 + kf) * 512;
#pragma unroll
        for (int i = 0; i < 4; i++) {
            int row = (tid >> 5) + 8 * i, quad = tid & 31;
            f32x4 v = *(const f32x4*)(src + (size_t)row * SZ + quad * 4);
            tile[row][quad * 4 + 0] = v.x; tile[row][quad * 4 + 1] = v.y;
            tile[row][quad * 4 + 2] = v.z; tile[row][quad * 4 + 3] = v.w;
        }
        __syncthreads();
#pragma unroll
        for (int ii = 0; ii < 2; ii++) {
            int hf = w * 2 + ii;
            bf16x8 o;
#pragma unroll
            for (int j = 0; j < 8; j++) {
                int kloc = (j < 4) ? (4 * lq + j) : (16 + 4 * lq + j - 4);
                o[j] = f2b(tile[kloc][hf * 16 + lr]);
            }
            *(bf16x8*)(dst + (size_t)hf * 4 * 512 + lane * 8) = o;
        }
        return;
    }
    int t = bid & 7, hh = (bid >> 3) & 1, tile = bid >> 4;
    int n = meta[t];
    int r0 = tile * 16;
    if (r0 >= n) return;
    int base = meta[16 + t];

    __shared__ int sg[16];
    __shared__ bf16_t xl[2][16][260];   // stride 260: <=2-way conflicts
    __shared__ bf16_t hl[16][68];       // local 64 h + pad
    if (tid < 16) {
        int r = r0 + tid;
        sg[tid] = idxb[base + (r < n ? r : n - 1)];
    }
    __syncthreads();

    // stage chunk 0: wave w loads rows 4w..4w+3, 256 f32 each, coalesced
    f32x4 pre[4];
#pragma unroll
    for (int rr = 0; rr < 4; rr++)
        pre[rr] = *(const f32x4*)(x + (size_t)sg[w * 4 + rr] * SZ + lane * 4);
#pragma unroll
    for (int rr = 0; rr < 4; rr++) {
        bf16x4 v = {f2b(pre[rr].x), f2b(pre[rr].y), f2b(pre[rr].z), f2b(pre[rr].w)};
        *(bf16x4*)(&xl[0][w * 4 + rr][lane * 4]) = v;
    }
    __syncthreads();

    // wave w computes hf = hh*4 + w (h = hh*64 + w*16 + lr)
    const bf16_t* wb = WdP + ((size_t)(t * 8 + hh * 4 + w) * 64) * 512 + lane * 8;
    f32x4 acc = {};
    for (int c = 0; c < 8; c++) {
        int cur = c & 1;
        if (c < 7) {
#pragma unroll
            for (int rr = 0; rr < 4; rr++)
                pre[rr] = *(const f32x4*)(x + (size_t)sg[w * 4 + rr] * SZ +
                                          (c + 1) * 256 + lane * 4);
        }
#pragma unroll
        for (int k8 = 0; k8 < 8; k8++) {
            int kf = c * 8 + k8;
            bf16x4 alo = *(const bf16x4*)(&xl[cur][lr][k8 * 32 + 4 * lq]);
            bf16x4 ahi = *(const bf16x4*)(&xl[cur][lr][k8 * 32 + 16 + 4 * lq]);
            bf16x8 a;
            a[0] = alo[0]; a[1] = alo[1]; a[2] = alo[2]; a[3] = alo[3];
            a[4] = ahi[0]; a[5] = ahi[1]; a[6] = ahi[2]; a[7] = ahi[3];
            bf16x8 b = *(const bf16x8*)(wb + (size_t)kf * 512);
            acc = __builtin_amdgcn_mfma_f32_16x16x32_bf16(a, b, acc, 0, 0, 0);
        }
        if (c < 7) {
#pragma unroll
            for (int rr = 0; rr < 4; rr++) {
                bf16x4 v = {f2b(pre[rr].x), f2b(pre[rr].y), f2b(pre[rr].z), f2b(pre[rr].w)};
                *(bf16x4*)(&xl[cur ^ 1][w * 4 + rr][lane * 4]) = v;
            }
        }
        __syncthreads();
    }

    // bias + silu -> hl (local h' = w*16+lr)
    {
        float bb = bd[t * HIDN + hh * 64 + w * 16 + lr];
#pragma unroll
        for (int reg = 0; reg < 4; reg++) {
            float v = acc[reg] + bb;
            hl[4 * lq + reg][w * 16 + lr] = f2b(v / (1.f + __expf(-v)));
        }
    }
    __syncthreads();
    // pack 2 kf slices (waves 0,1): global kf = hh*2 + s
    if (w < 2) {
        int rt = (base + r0) >> 4;
        bf16x8 o;
#pragma unroll
        for (int j = 0; j < 8; j++) {
            int k = w * 32 + ((j < 4) ? (4 * lq + j) : (16 + 4 * lq + j - 4));
            o[j] = hl[lr][k];
        }
        *(bf16x8*)(HbP + ((size_t)(rt * 4 + hh * 2 + w) * 64 + lane) * 8) = o;
    }
}

// ---- GEMM2 + residual + passthrough tail ----
// bid<16384: t = bid&7, tile = (bid>>3)&127 (32 rows), cchunk = bid>>10 (128 cols)
// bid>=16384: passthrough (bucket 8)
__global__ __launch_bounds__(256) void k_gemm2(const float* __restrict__ x,
                                               const bf16_t* __restrict__ WuP,
                                               const float* __restrict__ bu,
                                               const bf16_t* __restrict__ HbP,
                                               const int* __restrict__ idxb,
                                               const int* __restrict__ meta,
                                               float* __restrict__ out) {
    int bid = blockIdx.x;
    int tid = threadIdx.x;
    if (bid >= 16384) {
        int pb = bid - 16384;
        int n8 = meta[8];
        int tile = pb & 127, half = pb >> 7;
        int r0 = tile * 32;
        if (r0 >= n8) return;
        int base8 = meta[16 + 8];
        int row = tid >> 3, cq = tid & 7;
        int r = r0 + row;
        if (r < n8) {
            int g = idxb[base8 + r];
            const f32x4* xs = (const f32x4*)(x + (size_t)g * SZ + half * 256) + cq;
            f32x4* os = (f32x4*)(out + (size_t)g * SZ + half * 256) + cq;
#pragma unroll
            for (int j = 0; j < 8; j++) __builtin_nontemporal_store(xs[j * 8], &os[j * 8]);
        }
        return;
    }
    int t = bid & 7, tile = (bid >> 3) & 127, cchunk = bid >> 10;
    int n = meta[t];
    int r0 = tile * 32;
    if (r0 >= n) return;
    int base = meta[16 + t];
    int lane = tid & 63, w = tid >> 6;
    int wr = w & 1, wc = w >> 1, lr = lane & 15, lq = lane >> 4;

    int rt = (base + r0) / 16 + wr;           // base is 32-aligned
    const bf16_t* ap = HbP + (size_t)rt * 4 * 512 + lane * 8;
    bf16x8 a[4];
#pragma unroll
    for (int kf = 0; kf < 4; kf++) a[kf] = *(const bf16x8*)(ap + kf * 512);

    // block covers cols cchunk*128; wave covers wc*64 + cf*16
    const bf16_t* bp = WuP + ((size_t)(t * 128 + cchunk * 8 + wc * 4) * 4) * 512 + lane * 8;
    f32x4 acc[4] = {};
#pragma unroll
    for (int cf = 0; cf < 4; cf++) {
#pragma unroll
        for (int kf = 0; kf < 4; kf++) {
            bf16x8 b = *(const bf16x8*)(bp + (size_t)(cf * 4 + kf) * 512);
            acc[cf] = __builtin_amdgcn_mfma_f32_16x16x32_bf16(a[kf], b, acc[cf], 0, 0, 0);
        }
    }

    int gr[4];
#pragma unroll
    for (int reg = 0; reg < 4; reg++) {
        int r = r0 + wr * 16 + 4 * lq + reg;
        gr[reg] = (r < n) ? idxb[base + r] : -1;
    }
#pragma unroll
    for (int cf = 0; cf < 4; cf++) {
        int c = cchunk * 128 + wc * 64 + cf * 16 + lr;
        float bb = bu[t * SZ + c];
#pragma unroll
        for (int reg = 0; reg < 4; reg++) {
            if (gr[reg] >= 0) {
                size_t o = (size_t)gr[reg] * SZ + c;
                __builtin_nontemporal_store(x[o] + acc[cf][reg] + bb, &out[o]);
            }
        }
    }
}

extern "C" void kernel_launch(void* const* d_in, const int* in_sizes, int n_in,
                              void* d_out, int out_size, void* d_ws, size_t ws_size,
                              hipStream_t stream) {
    const float* x  = (const float*)d_in[0];
    const float* Wd = (const float*)d_in[1];
    const float* bd = (const float*)d_in[2];
    const float* Wu = (const float*)d_in[3];
    const float* bu = (const float*)d_in[4];
    const int* task = (const int*)d_in[5];
    float* out = (float*)d_out;

    char* ws = (char*)d_ws;
    int* idxb    = (int*)ws;
    int* meta    = (int*)(ws + 17664);
    int* cnt16   = (int*)(ws + 17920);
    bf16_t* HbP  = (bf16_t*)(ws + 18560);
    bf16_t* WdP  = (bf16_t*)(ws + 1140864);
    bf16_t* WuP  = (bf16_t*)(ws + 5335168);

    k_prep<<<528, 256, 0, stream>>>(Wd, task, WdP, cnt16);
    k_scatter<<<16, 256, 0, stream>>>(task, cnt16, meta, idxb);
    k_gemm1<<<4096 + 512, 256, 0, stream>>>(x, Wu, WdP, WuP, bd, idxb, meta, HbP);
    k_gemm2<<<16384 + 1024, 256, 0, stream>>>(x, WuP, bu, HbP, idxb, meta, out);
}